// Round 2
// baseline (760.210 us; speedup 1.0000x reference)
//
#include <hip/hip_runtime.h>
#include <hip/hip_bf16.h>
#include <stdint.h>

typedef __attribute__((ext_vector_type(8))) __bf16 bf16x8;
typedef __attribute__((ext_vector_type(8))) unsigned short ushort8;
typedef __attribute__((ext_vector_type(4))) float f32x4;

#define N_NODES 100000
#define N_EDGES 800000
#define FIN 128
#define FH 512
#define FO 40

// workspace byte offsets (16B-aligned where vector loads occur)
#define O_DINV   0ull            // N floats
#define O_CNT    400000ull       // N ints
#define O_ROWPTR 800000ull       // N+1 ints
#define O_CUR    1200016ull      // N ints
#define O_SRC    1600016ull      // E ints   (src sorted by dst)
#define O_DSRC   4800016ull      // E floats (dinv[src] sorted by dst)
#define O_W1T    8000016ull      // 512x128 bf16
#define O_W2T    8131088ull      // 48x512 bf16 (zero-padded cols 40..47)
#define O_H1     8180240ull      // N x 512 bf16
#define O_H2     110580240ull    // N x 40 f32
#define O_PART   126580240ull    // 128 ints
#define O_CBASE  126580752ull    // 128 ints
// total ws need ~126.6 MB

__device__ __forceinline__ unsigned short f2bf(float f) {
  unsigned u = __float_as_uint(f);
  u += 0x7fffu + ((u >> 16) & 1u);           // round-to-nearest-even
  return (unsigned short)(u >> 16);
}

__device__ __forceinline__ float bfu2f(unsigned short b) {
  return __uint_as_float(((unsigned)b) << 16);
}

__device__ __forceinline__ bf16x8 cvt8(const float* p) {
  ushort8 u;
#pragma unroll
  for (int j = 0; j < 8; j++) u[j] = f2bf(p[j]);
  return __builtin_bit_cast(bf16x8, u);
}

// ---------------- degree / CSR build ----------------

__global__ void k_count(const int* __restrict__ dst, int* __restrict__ cnt) {
  int e = blockIdx.x * 256 + threadIdx.x;
  if (e < N_EDGES) atomicAdd(&cnt[dst[e]], 1);
}

__global__ void k_dinv(const int* __restrict__ cnt, float* __restrict__ dinv) {
  int i = blockIdx.x * 256 + threadIdx.x;
  if (i < N_NODES) dinv[i] = 1.0f / sqrtf((float)(cnt[i] + 1)); // +1 self loop
}

__global__ void k_scan1(const int* __restrict__ cnt, int* __restrict__ rowptr,
                        int* __restrict__ partials) {
  __shared__ int s[1024];
  int t = threadIdx.x;
  int g = blockIdx.x * 1024 + t;
  int v = (g < N_NODES) ? cnt[g] : 0;
  s[t] = v; __syncthreads();
  for (int off = 1; off < 1024; off <<= 1) {
    int u = (t >= off) ? s[t - off] : 0;
    __syncthreads();
    s[t] += u;
    __syncthreads();
  }
  if (g < N_NODES) rowptr[g] = s[t] - v;     // chunk-local exclusive
  if (t == 1023) partials[blockIdx.x] = s[1023];
}

__global__ void k_scan2(const int* __restrict__ partials, int* __restrict__ chunk_base,
                        int nchunks) {
  __shared__ int s[128];
  int t = threadIdx.x;
  int v = (t < nchunks) ? partials[t] : 0;
  s[t] = v; __syncthreads();
  for (int off = 1; off < 128; off <<= 1) {
    int u = (t >= off) ? s[t - off] : 0;
    __syncthreads();
    s[t] += u;
    __syncthreads();
  }
  chunk_base[t] = s[t] - v;                  // exclusive
}

__global__ void k_scan3(int* __restrict__ rowptr, const int* __restrict__ chunk_base,
                        int* __restrict__ cur) {
  int g = blockIdx.x * 256 + threadIdx.x;
  if (g < N_NODES) {
    int v = rowptr[g] + chunk_base[g >> 10];
    rowptr[g] = v;
    cur[g] = v;
  } else if (g == N_NODES) {
    rowptr[N_NODES] = N_EDGES;
  }
}

__global__ void k_scatter(const int* __restrict__ src, const int* __restrict__ dst,
                          const float* __restrict__ dinv, int* __restrict__ cur,
                          int* __restrict__ src_sorted, float* __restrict__ dinv_src) {
  int e = blockIdx.x * 256 + threadIdx.x;
  if (e < N_EDGES) {
    int s = src[e];
    int d = dst[e];
    int pos = atomicAdd(&cur[d], 1);
    src_sorted[pos] = s;
    dinv_src[pos] = dinv[s];
  }
}

// ---------------- weight transposes (f32 -> bf16) ----------------

__global__ void k_tw1(const float* __restrict__ w1, unsigned short* __restrict__ w1t) {
  int t = blockIdx.x * 256 + threadIdx.x;    // 512*128
  int c = t >> 7, k = t & 127;
  w1t[c * 128 + k] = f2bf(w1[k * FH + c]);
}

__global__ void k_tw2(const float* __restrict__ w2, unsigned short* __restrict__ w2t) {
  int t = blockIdx.x * 256 + threadIdx.x;    // 48*512
  int c = t >> 9, k = t & 511;
  w2t[c * FH + k] = (c < FO) ? f2bf(w2[k * FO + c]) : (unsigned short)0;
}

// ---------------- dropout bits (JAX partitionable threefry, key=42) ----------------

__device__ __forceinline__ unsigned tf_bits(unsigned x0, unsigned x1) {
  const unsigned K0 = 0u, K1 = 42u, K2 = 0x1BD11BDAu ^ 42u;
  x0 += K0; x1 += K1;
#define RND(r) { x0 += x1; x1 = (x1 << (r)) | (x1 >> (32 - (r))); x1 ^= x0; }
  RND(13) RND(15) RND(26) RND(6)
  x0 += K1; x1 += K2 + 1u;
  RND(17) RND(29) RND(16) RND(24)
  x0 += K2; x1 += K0 + 2u;
  RND(13) RND(15) RND(26) RND(6)
  x0 += K0; x1 += K1 + 3u;
  RND(17) RND(29) RND(16) RND(24)
  x0 += K1; x1 += K2 + 4u;
  RND(13) RND(15) RND(26) RND(6)
  x0 += K2; x1 += K0 + 5u;
#undef RND
  return x0 ^ x1;   // partitionable path folds (out0, out1) by xor for 32-bit draws
}

// keep iff uniform(bits) < 0.5 iff top bit clear; kept values scaled by 2
__device__ __forceinline__ float dropout_val(float v, unsigned flat_idx) {
  unsigned bits = tf_bits(0u, flat_idx);     // counter = (hi=0, lo=flat)
  return (bits & 0x80000000u) ? 0.0f : v * 2.0f;
}

// ---------------- GEMM1: h1[N,512] = x[N,128] @ W1 (bf16 MFMA) ----------------
// 16x16x32 bf16. A: A[m=lane&15][k=(lane>>4)*8+j]. C/D: col=lane&15, row=(lane>>4)*4+reg.

__global__ __launch_bounds__(256) void k_gemm1(const float* __restrict__ x,
                                               const unsigned short* __restrict__ w1t,
                                               unsigned short* __restrict__ h1) {
  int w = threadIdx.x >> 6;
  int lane = threadIdx.x & 63;
  int m = lane & 15, kg = lane >> 4;
  int r0 = blockIdx.x * 32;                  // 32 rows per block
  int cw = w * 128;                          // 128 cols per wave
  f32x4 acc[2][8];
#pragma unroll
  for (int a = 0; a < 2; a++)
#pragma unroll
    for (int t = 0; t < 8; t++)
#pragma unroll
      for (int r = 0; r < 4; r++) acc[a][t][r] = 0.0f;

  const float* xa0 = x + (size_t)(r0 + m) * FIN + kg * 8;
  const float* xa1 = xa0 + 16 * FIN;
#pragma unroll
  for (int kc = 0; kc < 4; kc++) {
    int kb = kc * 32;
    bf16x8 a0 = cvt8(xa0 + kb);
    bf16x8 a1 = cvt8(xa1 + kb);
#pragma unroll
    for (int t = 0; t < 8; t++) {
      const unsigned short* bp = w1t + (size_t)(cw + t * 16 + m) * FIN + kb + kg * 8;
      bf16x8 b = __builtin_bit_cast(bf16x8, *(const ushort8*)bp);
      acc[0][t] = __builtin_amdgcn_mfma_f32_16x16x32_bf16(a0, b, acc[0][t], 0, 0, 0);
      acc[1][t] = __builtin_amdgcn_mfma_f32_16x16x32_bf16(a1, b, acc[1][t], 0, 0, 0);
    }
  }
#pragma unroll
  for (int rt = 0; rt < 2; rt++)
#pragma unroll
    for (int t = 0; t < 8; t++)
#pragma unroll
      for (int r = 0; r < 4; r++) {
        int row = r0 + rt * 16 + kg * 4 + r;
        int col = cw + t * 16 + m;
        h1[(size_t)row * FH + col] = f2bf(acc[rt][t][r]);
      }
}

// ---------------- aggregate L1 + bias + relu + dropout -> hidden (f32) ----------------
// one wave per node; lane owns channel pairs (2*lane, 2*lane+1) + 128*jj

__global__ __launch_bounds__(256) void k_agg1(const unsigned short* __restrict__ h1,
                                              const int* __restrict__ rowptr,
                                              const int* __restrict__ src_sorted,
                                              const float* __restrict__ dinv_src,
                                              const float* __restrict__ dinv,
                                              const float* __restrict__ b1,
                                              float* __restrict__ hidden) {
  int i = blockIdx.x * 4 + (threadIdx.x >> 6);
  int lane = threadIdx.x & 63;
  int rs = rowptr[i], re = rowptr[i + 1];
  float di = dinv[i];
  float acc[8] = {0, 0, 0, 0, 0, 0, 0, 0};
  int cbase = 2 * lane;

  for (int e = rs; e < re; e++) {
    int s = src_sorted[e];
    float wgt = dinv_src[e];
    const unsigned short* hp = h1 + (size_t)s * FH + cbase;
#pragma unroll
    for (int jj = 0; jj < 4; jj++) {
      unsigned v = *(const unsigned*)(hp + jj * 128);
      acc[2 * jj]     += wgt * __uint_as_float(v << 16);
      acc[2 * jj + 1] += wgt * __uint_as_float(v & 0xffff0000u);
    }
  }
  { // self loop, weight dinv[i]
    const unsigned short* hp = h1 + (size_t)i * FH + cbase;
#pragma unroll
    for (int jj = 0; jj < 4; jj++) {
      unsigned v = *(const unsigned*)(hp + jj * 128);
      acc[2 * jj]     += di * __uint_as_float(v << 16);
      acc[2 * jj + 1] += di * __uint_as_float(v & 0xffff0000u);
    }
  }
#pragma unroll
  for (int jj = 0; jj < 4; jj++) {
    int c = cbase + jj * 128;
    float v0 = acc[2 * jj] * di + b1[c];
    float v1 = acc[2 * jj + 1] * di + b1[c + 1];
    v0 = fmaxf(v0, 0.0f);
    v1 = fmaxf(v1, 0.0f);
    unsigned flat = (unsigned)i * FH + (unsigned)c;
    v0 = dropout_val(v0, flat);
    v1 = dropout_val(v1, flat + 1u);
    float2 st; st.x = v0; st.y = v1;
    *(float2*)(hidden + (size_t)i * FH + c) = st;
  }
}

// ---------------- GEMM2: h2[N,40] = hidden[N,512] @ W2 (bf16 MFMA, cols padded 48) ----------------

__global__ __launch_bounds__(256) void k_gemm2(const float* __restrict__ hidden,
                                               const unsigned short* __restrict__ w2t,
                                               float* __restrict__ h2) {
  int wid = blockIdx.x * 4 + (threadIdx.x >> 6);
  if (wid >= N_NODES / 16) return;
  int lane = threadIdx.x & 63;
  int m = lane & 15, kg = lane >> 4;
  int r0 = wid * 16;
  f32x4 acc[3];
#pragma unroll
  for (int t = 0; t < 3; t++)
#pragma unroll
    for (int r = 0; r < 4; r++) acc[t][r] = 0.0f;

  const float* ap = hidden + (size_t)(r0 + m) * FH + kg * 8;
#pragma unroll 4
  for (int kc = 0; kc < 16; kc++) {
    int kb = kc * 32;
    bf16x8 a = cvt8(ap + kb);
#pragma unroll
    for (int t = 0; t < 3; t++) {
      bf16x8 b = __builtin_bit_cast(bf16x8,
          *(const ushort8*)(w2t + (size_t)(t * 16 + m) * FH + kb + kg * 8));
      acc[t] = __builtin_amdgcn_mfma_f32_16x16x32_bf16(a, b, acc[t], 0, 0, 0);
    }
  }
#pragma unroll
  for (int t = 0; t < 3; t++)
#pragma unroll
    for (int r = 0; r < 4; r++) {
      int row = r0 + kg * 4 + r;
      int col = t * 16 + m;
      if (col < FO) h2[(size_t)row * FO + col] = acc[t][r];
    }
}

// ---------------- aggregate L2 + bias -> out (f32) ----------------

__global__ __launch_bounds__(256) void k_agg2(const float* __restrict__ h2,
                                              const int* __restrict__ rowptr,
                                              const int* __restrict__ src_sorted,
                                              const float* __restrict__ dinv_src,
                                              const float* __restrict__ dinv,
                                              const float* __restrict__ b2,
                                              float* __restrict__ out) {
  int i = blockIdx.x * 4 + (threadIdx.x >> 6);
  int lane = threadIdx.x & 63;
  if (lane >= FO) return;
  int rs = rowptr[i], re = rowptr[i + 1];
  float di = dinv[i];
  float acc = 0.0f;
  for (int e = rs; e < re; e++) {
    acc += dinv_src[e] * h2[(size_t)src_sorted[e] * FO + lane];
  }
  acc += di * h2[(size_t)i * FO + lane];
  out[(size_t)i * FO + lane] = acc * di + b2[lane];
}

// ---------------- launcher ----------------

extern "C" void kernel_launch(void* const* d_in, const int* in_sizes, int n_in,
                              void* d_out, int out_size, void* d_ws, size_t ws_size,
                              hipStream_t stream) {
  const float* x  = (const float*)d_in[0];
  const int* ei   = (const int*)d_in[1];
  const float* w1 = (const float*)d_in[2];
  const float* b1 = (const float*)d_in[3];
  const float* w2 = (const float*)d_in[4];
  const float* b2 = (const float*)d_in[5];

  char* ws = (char*)d_ws;
  float* dinv            = (float*)(ws + O_DINV);
  int* cnt               = (int*)(ws + O_CNT);
  int* rowptr            = (int*)(ws + O_ROWPTR);
  int* cur               = (int*)(ws + O_CUR);
  int* src_sorted        = (int*)(ws + O_SRC);
  float* dinv_src        = (float*)(ws + O_DSRC);
  unsigned short* w1t    = (unsigned short*)(ws + O_W1T);
  unsigned short* w2t    = (unsigned short*)(ws + O_W2T);
  unsigned short* h1     = (unsigned short*)(ws + O_H1);
  float* h2              = (float*)(ws + O_H2);
  int* partials          = (int*)(ws + O_PART);
  int* chunk_base        = (int*)(ws + O_CBASE);

  float* outp   = (float*)d_out;                       // [N,40]
  float* hidden = outp + (size_t)N_NODES * FO;         // [N,512]

  const int* srcA = ei;             // edge_index[0]
  const int* dstA = ei + N_EDGES;   // edge_index[1]

  hipMemsetAsync(cnt, 0, N_NODES * sizeof(int), stream);
  k_count<<<(N_EDGES + 255) / 256, 256, 0, stream>>>(dstA, cnt);
  k_dinv<<<(N_NODES + 255) / 256, 256, 0, stream>>>(cnt, dinv);
  k_scan1<<<(N_NODES + 1023) / 1024, 1024, 0, stream>>>(cnt, rowptr, partials);
  k_scan2<<<1, 128, 0, stream>>>(partials, chunk_base, (N_NODES + 1023) / 1024);
  k_scan3<<<(N_NODES + 1 + 255) / 256, 256, 0, stream>>>(rowptr, chunk_base, cur);
  k_scatter<<<(N_EDGES + 255) / 256, 256, 0, stream>>>(srcA, dstA, dinv, cur,
                                                       src_sorted, dinv_src);
  k_tw1<<<(FIN * FH) / 256, 256, 0, stream>>>(w1, w1t);
  k_tw2<<<(48 * FH) / 256, 256, 0, stream>>>(w2, w2t);
  k_gemm1<<<N_NODES / 32, 256, 0, stream>>>(x, w1t, h1);
  k_agg1<<<N_NODES / 4, 256, 0, stream>>>(h1, rowptr, src_sorted, dinv_src, dinv,
                                          b1, hidden);
  k_gemm2<<<(N_NODES / 16 + 3) / 4, 256, 0, stream>>>(hidden, w2t, h2);
  k_agg2<<<N_NODES / 4, 256, 0, stream>>>(h2, rowptr, src_sorted, dinv_src, dinv,
                                          b2, outp);
}

// Round 3
// 745.309 us; speedup vs baseline: 1.0200x; 1.0200x over previous
//
#include <hip/hip_runtime.h>
#include <hip/hip_bf16.h>
#include <stdint.h>

typedef __attribute__((ext_vector_type(8))) __bf16 bf16x8;
typedef __attribute__((ext_vector_type(8))) unsigned short ushort8;
typedef __attribute__((ext_vector_type(4))) float f32x4;

#define N_NODES 100000
#define N_EDGES 800000
#define FIN 128
#define FH 512
#define FO 40
#define NCHUNK 391   // ceil(N/256)

// workspace byte offsets (16B-aligned where vector loads occur)
#define O_DINV   0ull            // N floats
#define O_CNT    400000ull       // N ints
#define O_ROWPTR 800000ull       // N+1 ints
#define O_CUR    1200016ull      // N ints
#define O_SRC    1600016ull      // E ints   (src sorted by dst)
#define O_DSRC   4800016ull      // E floats (dinv[src] sorted by dst)
#define O_W1T    8000016ull      // 512x128 bf16
#define O_W2T    8131088ull      // 48x512 bf16 (zero-padded cols 40..47)
#define O_H1     8180240ull      // N x 512 bf16
#define O_H2     110580240ull    // N x 40 f32
#define O_PART   126580240ull    // 512 ints
#define O_CBASE  126582288ull    // 512 ints
// total ws need ~126.59 MB (same footprint as the round that passed)

__device__ __forceinline__ unsigned short f2bf(float f) {
  unsigned u = __float_as_uint(f);
  u += 0x7fffu + ((u >> 16) & 1u);           // round-to-nearest-even
  return (unsigned short)(u >> 16);
}

__device__ __forceinline__ float blo(unsigned v) { return __uint_as_float(v << 16); }
__device__ __forceinline__ float bhi(unsigned v) { return __uint_as_float(v & 0xffff0000u); }

// truncating f32x8 -> bf16x8 pack, 1 v_perm_b32 per pair (staging for MFMA A)
__device__ __forceinline__ bf16x8 cvt8t(const float* p) {
  uint4 a = *(const uint4*)p;
  uint4 b = *(const uint4*)(p + 4);
  uint4 w;
  w.x = __builtin_amdgcn_perm(a.y, a.x, 0x07060302u);
  w.y = __builtin_amdgcn_perm(a.w, a.z, 0x07060302u);
  w.z = __builtin_amdgcn_perm(b.y, b.x, 0x07060302u);
  w.w = __builtin_amdgcn_perm(b.w, b.z, 0x07060302u);
  return __builtin_bit_cast(bf16x8, w);
}

// ---------------- degree / CSR build ----------------

__global__ void k_count(const int* __restrict__ dst, int* __restrict__ cnt) {
  int e = blockIdx.x * 256 + threadIdx.x;
  if (e < N_EDGES) atomicAdd(&cnt[dst[e]], 1);
}

__global__ void k_dinv(const int* __restrict__ cnt, float* __restrict__ dinv) {
  int i = blockIdx.x * 256 + threadIdx.x;
  if (i < N_NODES) dinv[i] = 1.0f / sqrtf((float)(cnt[i] + 1)); // +1 self loop
}

__global__ void k_scan1(const int* __restrict__ cnt, int* __restrict__ rowptr,
                        int* __restrict__ partials) {
  int t = threadIdx.x, g = blockIdx.x * 256 + t;
  int v = (g < N_NODES) ? cnt[g] : 0;
  int lane = t & 63, w = t >> 6;
  int sc = v;
#pragma unroll
  for (int off = 1; off < 64; off <<= 1) {
    int u = __shfl_up(sc, off);
    if (lane >= off) sc += u;
  }
  __shared__ int wsum[4];
  if (lane == 63) wsum[w] = sc;
  __syncthreads();
  int add = 0;
  for (int j = 0; j < w; j++) add += wsum[j];
  int incl = sc + add;
  if (g < N_NODES) rowptr[g] = incl - v;     // chunk-local exclusive
  if (t == 255) partials[blockIdx.x] = incl;
}

__global__ void k_scan2(const int* __restrict__ partials, int* __restrict__ chunk_base) {
  __shared__ int s[512];
  int t = threadIdx.x;
  int v = (t < NCHUNK) ? partials[t] : 0;
  s[t] = v; __syncthreads();
  for (int off = 1; off < 512; off <<= 1) {
    int u = (t >= off) ? s[t - off] : 0;
    __syncthreads();
    s[t] += u;
    __syncthreads();
  }
  chunk_base[t] = s[t] - v;                  // exclusive
}

__global__ void k_scan3(int* __restrict__ rowptr, const int* __restrict__ chunk_base,
                        int* __restrict__ cur) {
  int g = blockIdx.x * 256 + threadIdx.x;
  if (g < N_NODES) {
    int v = rowptr[g] + chunk_base[g >> 8];
    rowptr[g] = v;
    cur[g] = v;
  } else if (g == N_NODES) {
    rowptr[N_NODES] = N_EDGES;
  }
}

__global__ void k_scatter(const int* __restrict__ src, const int* __restrict__ dst,
                          const float* __restrict__ dinv, int* __restrict__ cur,
                          int* __restrict__ src_sorted, float* __restrict__ dinv_src) {
  int e = blockIdx.x * 256 + threadIdx.x;
  if (e < N_EDGES) {
    int s = src[e];
    int d = dst[e];
    int pos = atomicAdd(&cur[d], 1);
    src_sorted[pos] = s;
    dinv_src[pos] = dinv[s];
  }
}

// ---------------- weight transposes (f32 -> bf16, RNE) ----------------

__global__ void k_tw1(const float* __restrict__ w1, unsigned short* __restrict__ w1t) {
  int t = blockIdx.x * 256 + threadIdx.x;    // 512*128
  int c = t >> 7, k = t & 127;
  w1t[c * 128 + k] = f2bf(w1[k * FH + c]);
}

__global__ void k_tw2(const float* __restrict__ w2, unsigned short* __restrict__ w2t) {
  int t = blockIdx.x * 256 + threadIdx.x;    // 48*512
  int c = t >> 9, k = t & 511;
  w2t[c * FH + k] = (c < FO) ? f2bf(w2[k * FO + c]) : (unsigned short)0;
}

// ---------------- dropout bits (JAX partitionable threefry, key=42) ----------------

__device__ __forceinline__ unsigned tf_bits(unsigned x0, unsigned x1) {
  const unsigned K0 = 0u, K1 = 42u, K2 = 0x1BD11BDAu ^ 42u;
  x0 += K0; x1 += K1;
#define RND(r) { x0 += x1; x1 = (x1 << (r)) | (x1 >> (32 - (r))); x1 ^= x0; }
  RND(13) RND(15) RND(26) RND(6)
  x0 += K1; x1 += K2 + 1u;
  RND(17) RND(29) RND(16) RND(24)
  x0 += K2; x1 += K0 + 2u;
  RND(13) RND(15) RND(26) RND(6)
  x0 += K0; x1 += K1 + 3u;
  RND(17) RND(29) RND(16) RND(24)
  x0 += K1; x1 += K2 + 4u;
  RND(13) RND(15) RND(26) RND(6)
  x0 += K2; x1 += K0 + 5u;
#undef RND
  return x0 ^ x1;   // partitionable path xor-folds (out0, out1)
}

// ---------------- GEMM1: h1[N,512] = x[N,128] @ W1 (bf16 MFMA) ----------------
// 16x16x32 bf16. A: A[m=lane&15][k=(lane>>4)*8+j]. C/D: col=lane&15, row=(lane>>4)*4+reg.

__global__ __launch_bounds__(256) void k_gemm1(const float* __restrict__ x,
                                               const unsigned short* __restrict__ w1t,
                                               unsigned short* __restrict__ h1) {
  int w = threadIdx.x >> 6;
  int lane = threadIdx.x & 63;
  int m = lane & 15, kg = lane >> 4;
  int r0 = blockIdx.x * 32;                  // 32 rows per block
  int cw = w * 128;                          // 128 cols per wave
  f32x4 acc[2][8];
#pragma unroll
  for (int a = 0; a < 2; a++)
#pragma unroll
    for (int t = 0; t < 8; t++)
#pragma unroll
      for (int r = 0; r < 4; r++) acc[a][t][r] = 0.0f;

  const float* xa0 = x + (size_t)(r0 + m) * FIN + kg * 8;
  const float* xa1 = xa0 + 16 * FIN;
#pragma unroll
  for (int kc = 0; kc < 4; kc++) {
    int kb = kc * 32;
    bf16x8 a0 = cvt8t(xa0 + kb);
    bf16x8 a1 = cvt8t(xa1 + kb);
#pragma unroll
    for (int t = 0; t < 8; t++) {
      const unsigned short* bp = w1t + (size_t)(cw + t * 16 + m) * FIN + kb + kg * 8;
      bf16x8 b = __builtin_bit_cast(bf16x8, *(const ushort8*)bp);
      acc[0][t] = __builtin_amdgcn_mfma_f32_16x16x32_bf16(a0, b, acc[0][t], 0, 0, 0);
      acc[1][t] = __builtin_amdgcn_mfma_f32_16x16x32_bf16(a1, b, acc[1][t], 0, 0, 0);
    }
  }
#pragma unroll
  for (int rt = 0; rt < 2; rt++)
#pragma unroll
    for (int t = 0; t < 8; t++)
#pragma unroll
      for (int r = 0; r < 4; r++) {
        int row = r0 + rt * 16 + kg * 4 + r;
        int col = cw + t * 16 + m;
        h1[(size_t)row * FH + col] = f2bf(acc[rt][t][r]);
      }
}

// ---------------- aggregate L1 + bias + relu + dropout -> hidden (f32) ----------------
// one wave per node; lane owns 8 contiguous channels [8*lane, 8*lane+8)
// edge idx/weight batch-prefetched into lanes, broadcast by readlane.

__global__ __launch_bounds__(256) void k_agg1(const unsigned short* __restrict__ h1,
                                              const int* __restrict__ rowptr,
                                              const int* __restrict__ src_sorted,
                                              const float* __restrict__ dinv_src,
                                              const float* __restrict__ dinv,
                                              const float* __restrict__ b1,
                                              float* __restrict__ hidden) {
  int i = blockIdx.x * 4 + (threadIdx.x >> 6);
  int lane = threadIdx.x & 63;
  int rs = rowptr[i], re = rowptr[i + 1];
  float di = dinv[i];
  int c = lane << 3;                         // 8 channels per lane

  // dropout mask bits for my 8 channels (bit j set = DROP)
  unsigned flat = (unsigned)i * FH + (unsigned)c;
  unsigned mb = 0;
#pragma unroll
  for (int j = 0; j < 8; j++) mb |= (tf_bits(0u, flat + j) >> 31) << j;

  float acc[8] = {0, 0, 0, 0, 0, 0, 0, 0};

  for (int base = rs; base < re; base += 64) {
    int n = re - base; if (n > 64) n = 64;
    int myi = 0; float myw = 0.0f;
    if (lane < n) { myi = src_sorted[base + lane]; myw = dinv_src[base + lane]; }
    for (int j = 0; j < n; j++) {
      int s = __shfl(myi, j);
      float wgt = __shfl(myw, j);
      uint4 hv = *(const uint4*)(h1 + (size_t)s * FH + c);
      acc[0] += wgt * blo(hv.x); acc[1] += wgt * bhi(hv.x);
      acc[2] += wgt * blo(hv.y); acc[3] += wgt * bhi(hv.y);
      acc[4] += wgt * blo(hv.z); acc[5] += wgt * bhi(hv.z);
      acc[6] += wgt * blo(hv.w); acc[7] += wgt * bhi(hv.w);
    }
  }
  { // self loop, weight di
    uint4 hv = *(const uint4*)(h1 + (size_t)i * FH + c);
    acc[0] += di * blo(hv.x); acc[1] += di * bhi(hv.x);
    acc[2] += di * blo(hv.y); acc[3] += di * bhi(hv.y);
    acc[4] += di * blo(hv.z); acc[5] += di * bhi(hv.z);
    acc[6] += di * blo(hv.w); acc[7] += di * bhi(hv.w);
  }

  float4 bA = *(const float4*)(b1 + c);
  float4 bB = *(const float4*)(b1 + c + 4);
  float bv[8] = {bA.x, bA.y, bA.z, bA.w, bB.x, bB.y, bB.z, bB.w};
  float outv[8];
#pragma unroll
  for (int j = 0; j < 8; j++) {
    float v = fmaxf(acc[j] * di + bv[j], 0.0f);
    outv[j] = ((mb >> j) & 1u) ? 0.0f : v * 2.0f;
  }
  float* hp = hidden + (size_t)i * FH + c;
  *(float4*)hp = make_float4(outv[0], outv[1], outv[2], outv[3]);
  *(float4*)(hp + 4) = make_float4(outv[4], outv[5], outv[6], outv[7]);
}

// ---------------- GEMM2: h2[N,40] = hidden[N,512] @ W2 (bf16 MFMA, cols padded 48) ----------------

__global__ __launch_bounds__(256) void k_gemm2(const float* __restrict__ hidden,
                                               const unsigned short* __restrict__ w2t,
                                               float* __restrict__ h2) {
  int wid = blockIdx.x * 4 + (threadIdx.x >> 6);
  if (wid >= N_NODES / 16) return;
  int lane = threadIdx.x & 63;
  int m = lane & 15, kg = lane >> 4;
  int r0 = wid * 16;
  f32x4 acc[3];
#pragma unroll
  for (int t = 0; t < 3; t++)
#pragma unroll
    for (int r = 0; r < 4; r++) acc[t][r] = 0.0f;

  const float* ap = hidden + (size_t)(r0 + m) * FH + kg * 8;
#pragma unroll 8
  for (int kc = 0; kc < 16; kc++) {
    int kb = kc * 32;
    bf16x8 a = cvt8t(ap + kb);
#pragma unroll
    for (int t = 0; t < 3; t++) {
      bf16x8 b = __builtin_bit_cast(bf16x8,
          *(const ushort8*)(w2t + (size_t)(t * 16 + m) * FH + kb + kg * 8));
      acc[t] = __builtin_amdgcn_mfma_f32_16x16x32_bf16(a, b, acc[t], 0, 0, 0);
    }
  }
#pragma unroll
  for (int t = 0; t < 3; t++)
#pragma unroll
    for (int r = 0; r < 4; r++) {
      int row = r0 + kg * 4 + r;
      int col = t * 16 + m;
      if (col < FO) h2[(size_t)row * FO + col] = acc[t][r];
    }
}

// ---------------- aggregate L2 + bias -> out (f32) ----------------

__global__ __launch_bounds__(256) void k_agg2(const float* __restrict__ h2,
                                              const int* __restrict__ rowptr,
                                              const int* __restrict__ src_sorted,
                                              const float* __restrict__ dinv_src,
                                              const float* __restrict__ dinv,
                                              const float* __restrict__ b2,
                                              float* __restrict__ out) {
  int i = blockIdx.x * 4 + (threadIdx.x >> 6);
  int lane = threadIdx.x & 63;
  int rs = rowptr[i], re = rowptr[i + 1];
  float di = dinv[i];
  float acc = 0.0f;

  for (int base = rs; base < re; base += 64) {
    int n = re - base; if (n > 64) n = 64;
    int myi = 0; float myw = 0.0f;
    if (lane < n) { myi = src_sorted[base + lane]; myw = dinv_src[base + lane]; }
    for (int j = 0; j < n; j++) {
      int s = __shfl(myi, j);
      float wgt = __shfl(myw, j);
      if (lane < FO) acc += wgt * h2[(size_t)s * FO + lane];
    }
  }
  if (lane < FO) {
    acc += di * h2[(size_t)i * FO + lane];
    out[(size_t)i * FO + lane] = acc * di + b2[lane];
  }
}

// ---------------- launcher ----------------

extern "C" void kernel_launch(void* const* d_in, const int* in_sizes, int n_in,
                              void* d_out, int out_size, void* d_ws, size_t ws_size,
                              hipStream_t stream) {
  const float* x  = (const float*)d_in[0];
  const int* ei   = (const int*)d_in[1];
  const float* w1 = (const float*)d_in[2];
  const float* b1 = (const float*)d_in[3];
  const float* w2 = (const float*)d_in[4];
  const float* b2 = (const float*)d_in[5];

  char* ws = (char*)d_ws;
  float* dinv            = (float*)(ws + O_DINV);
  int* cnt               = (int*)(ws + O_CNT);
  int* rowptr            = (int*)(ws + O_ROWPTR);
  int* cur               = (int*)(ws + O_CUR);
  int* src_sorted        = (int*)(ws + O_SRC);
  float* dinv_src        = (float*)(ws + O_DSRC);
  unsigned short* w1t    = (unsigned short*)(ws + O_W1T);
  unsigned short* w2t    = (unsigned short*)(ws + O_W2T);
  unsigned short* h1     = (unsigned short*)(ws + O_H1);
  float* h2              = (float*)(ws + O_H2);
  int* partials          = (int*)(ws + O_PART);
  int* chunk_base        = (int*)(ws + O_CBASE);

  float* outp   = (float*)d_out;                       // [N,40]
  float* hidden = outp + (size_t)N_NODES * FO;         // [N,512]

  const int* srcA = ei;             // edge_index[0]
  const int* dstA = ei + N_EDGES;   // edge_index[1]

  hipMemsetAsync(cnt, 0, N_NODES * sizeof(int), stream);
  k_count<<<(N_EDGES + 255) / 256, 256, 0, stream>>>(dstA, cnt);
  k_dinv<<<(N_NODES + 255) / 256, 256, 0, stream>>>(cnt, dinv);
  k_scan1<<<NCHUNK, 256, 0, stream>>>(cnt, rowptr, partials);
  k_scan2<<<1, 512, 0, stream>>>(partials, chunk_base);
  k_scan3<<<(N_NODES + 1 + 255) / 256, 256, 0, stream>>>(rowptr, chunk_base, cur);
  k_scatter<<<(N_EDGES + 255) / 256, 256, 0, stream>>>(srcA, dstA, dinv, cur,
                                                       src_sorted, dinv_src);
  k_tw1<<<(FIN * FH) / 256, 256, 0, stream>>>(w1, w1t);
  k_tw2<<<(48 * FH) / 256, 256, 0, stream>>>(w2, w2t);
  k_gemm1<<<N_NODES / 32, 256, 0, stream>>>(x, w1t, h1);
  k_agg1<<<N_NODES / 4, 256, 0, stream>>>(h1, rowptr, src_sorted, dinv_src, dinv,
                                          b1, hidden);
  k_gemm2<<<(N_NODES / 16 + 3) / 4, 256, 0, stream>>>(hidden, w2t, h2);
  k_agg2<<<N_NODES / 4, 256, 0, stream>>>(h2, rowptr, src_sorted, dinv_src, dinv,
                                          b2, outp);
}

// Round 4
// 745.258 us; speedup vs baseline: 1.0201x; 1.0001x over previous
//
#include <hip/hip_runtime.h>
#include <hip/hip_bf16.h>
#include <stdint.h>

typedef __attribute__((ext_vector_type(8))) __bf16 bf16x8;
typedef __attribute__((ext_vector_type(8))) unsigned short ushort8;
typedef __attribute__((ext_vector_type(4))) float f32x4;
typedef __attribute__((ext_vector_type(4))) unsigned int u32x4;

#define N_NODES 100000
#define N_EDGES 800000
#define FIN 128
#define FH 512
#define FO 40
#define NCHUNK 391   // ceil(N/256)

// workspace byte offsets (16B-aligned where vector loads occur)
#define O_DINV   0ull            // N floats
#define O_CNT    400000ull       // N ints
#define O_ROWPTR 800000ull       // N+1 ints
#define O_CUR    1200016ull      // N ints
#define O_SRC    1600016ull      // E ints   (src sorted by dst)
#define O_DSRC   4800016ull      // E floats (dinv[src] sorted by dst)
#define O_W1T    8000016ull      // 512x128 bf16
#define O_W2T    8131088ull      // 48x512 bf16 (zero-padded cols 40..47)
#define O_H1     8180240ull      // N x 512 bf16
#define O_H2     110580240ull    // N x 40 f32
#define O_PART   126580240ull    // 512 ints
#define O_CBASE  126582288ull    // 512 ints

__device__ __forceinline__ unsigned short f2bf(float f) {
  unsigned u = __float_as_uint(f);
  u += 0x7fffu + ((u >> 16) & 1u);           // round-to-nearest-even
  return (unsigned short)(u >> 16);
}

__device__ __forceinline__ float blo(unsigned v) { return __uint_as_float(v << 16); }
__device__ __forceinline__ float bhi(unsigned v) { return __uint_as_float(v & 0xffff0000u); }

// truncating f32x8 -> bf16x8 pack from registers (staging for MFMA A)
__device__ __forceinline__ bf16x8 pack8t(u32x4 a, u32x4 b) {
  u32x4 w;
  w.x = __builtin_amdgcn_perm(a.y, a.x, 0x07060302u);
  w.y = __builtin_amdgcn_perm(a.w, a.z, 0x07060302u);
  w.z = __builtin_amdgcn_perm(b.y, b.x, 0x07060302u);
  w.w = __builtin_amdgcn_perm(b.w, b.z, 0x07060302u);
  return __builtin_bit_cast(bf16x8, w);
}

// ---------------- degree / CSR build ----------------

__global__ void k_count(const int* __restrict__ dst, int* __restrict__ cnt) {
  int e = blockIdx.x * 256 + threadIdx.x;
  if (e < N_EDGES) atomicAdd(&cnt[__builtin_nontemporal_load(&dst[e])], 1);
}

// scan over cnt (chunk-local) + dinv = rsqrt(cnt+1) fused
__global__ void k_scan1(const int* __restrict__ cnt, int* __restrict__ rowptr,
                        int* __restrict__ partials, float* __restrict__ dinv) {
  int t = threadIdx.x, g = blockIdx.x * 256 + t;
  int v = (g < N_NODES) ? cnt[g] : 0;
  if (g < N_NODES) dinv[g] = __frsqrt_rn((float)(v + 1));
  int lane = t & 63, w = t >> 6;
  int sc = v;
#pragma unroll
  for (int off = 1; off < 64; off <<= 1) {
    int u = __shfl_up(sc, off);
    if (lane >= off) sc += u;
  }
  __shared__ int wsum[4];
  if (lane == 63) wsum[w] = sc;
  __syncthreads();
  int add = 0;
  for (int j = 0; j < w; j++) add += wsum[j];
  int incl = sc + add;
  if (g < N_NODES) rowptr[g] = incl - v;     // chunk-local exclusive
  if (t == 255) partials[blockIdx.x] = incl;
}

__global__ void k_scan2(const int* __restrict__ partials, int* __restrict__ chunk_base) {
  __shared__ int s[512];
  int t = threadIdx.x;
  int v = (t < NCHUNK) ? partials[t] : 0;
  s[t] = v; __syncthreads();
  for (int off = 1; off < 512; off <<= 1) {
    int u = (t >= off) ? s[t - off] : 0;
    __syncthreads();
    s[t] += u;
    __syncthreads();
  }
  chunk_base[t] = s[t] - v;                  // exclusive
}

__global__ void k_scan3(int* __restrict__ rowptr, const int* __restrict__ chunk_base,
                        int* __restrict__ cur) {
  int g = blockIdx.x * 256 + threadIdx.x;
  if (g < N_NODES) {
    int v = rowptr[g] + chunk_base[g >> 8];
    rowptr[g] = v;
    cur[g] = v;
  } else if (g == N_NODES) {
    rowptr[N_NODES] = N_EDGES;
  }
}

__global__ void k_scatter(const int* __restrict__ src, const int* __restrict__ dst,
                          const float* __restrict__ dinv, int* __restrict__ cur,
                          int* __restrict__ src_sorted, float* __restrict__ dinv_src) {
  int e = blockIdx.x * 256 + threadIdx.x;
  if (e < N_EDGES) {
    int s = __builtin_nontemporal_load(&src[e]);
    int d = __builtin_nontemporal_load(&dst[e]);
    int pos = atomicAdd(&cur[d], 1);
    src_sorted[pos] = s;
    dinv_src[pos] = dinv[s];
  }
}

// ---------------- weight transposes (f32 -> bf16, RNE), fused ----------------

__global__ void k_tw(const float* __restrict__ w1, const float* __restrict__ w2,
                     unsigned short* __restrict__ w1t, unsigned short* __restrict__ w2t) {
  int t = blockIdx.x * 256 + threadIdx.x;
  if (t < FIN * FH) {                        // 65536: W1^T
    int c = t >> 7, k = t & 127;
    w1t[c * 128 + k] = f2bf(w1[k * FH + c]);
  } else {
    int u = t - FIN * FH;                    // 48*512: W2^T (pad cols 40..47)
    int c = u >> 9, k = u & 511;
    w2t[c * FH + k] = (c < FO) ? f2bf(w2[k * FO + c]) : (unsigned short)0;
  }
}

// ---------------- dropout bits (JAX partitionable threefry, key=42) ----------------

__device__ __forceinline__ unsigned tf_bits(unsigned x0, unsigned x1) {
  const unsigned K0 = 0u, K1 = 42u, K2 = 0x1BD11BDAu ^ 42u;
  x0 += K0; x1 += K1;
#define RND(r) { x0 += x1; x1 = (x1 << (r)) | (x1 >> (32 - (r))); x1 ^= x0; }
  RND(13) RND(15) RND(26) RND(6)
  x0 += K1; x1 += K2 + 1u;
  RND(17) RND(29) RND(16) RND(24)
  x0 += K2; x1 += K0 + 2u;
  RND(13) RND(15) RND(26) RND(6)
  x0 += K0; x1 += K1 + 3u;
  RND(17) RND(29) RND(16) RND(24)
  x0 += K1; x1 += K2 + 4u;
  RND(13) RND(15) RND(26) RND(6)
  x0 += K2; x1 += K0 + 5u;
#undef RND
  return x0 ^ x1;   // partitionable path xor-folds (out0, out1)
}

// ---------------- GEMM1: h1[N,512] = x[N,128] @ W1 (bf16 MFMA) ----------------
// 16x16x32 bf16. A: A[m=lane&15][k=(lane>>4)*8+j]. C/D: col=lane&15, row=(lane>>4)*4+reg.

__global__ __launch_bounds__(256) void k_gemm1(const float* __restrict__ x,
                                               const unsigned short* __restrict__ w1t,
                                               unsigned short* __restrict__ h1) {
  int w = threadIdx.x >> 6;
  int lane = threadIdx.x & 63;
  int m = lane & 15, kg = lane >> 4;
  int r0 = blockIdx.x * 32;                  // 32 rows per block
  int cw = w * 128;                          // 128 cols per wave
  f32x4 acc[2][8];
#pragma unroll
  for (int a = 0; a < 2; a++)
#pragma unroll
    for (int t = 0; t < 8; t++)
#pragma unroll
      for (int r = 0; r < 4; r++) acc[a][t][r] = 0.0f;

  const float* xa0 = x + (size_t)(r0 + m) * FIN + kg * 8;
  const float* xa1 = xa0 + 16 * FIN;
#pragma unroll
  for (int kc = 0; kc < 4; kc++) {
    int kb = kc * 32;
    // x is read exactly once: non-temporal, keep LLC for h1
    u32x4 a0l = __builtin_nontemporal_load((const u32x4*)(xa0 + kb));
    u32x4 a0h = __builtin_nontemporal_load((const u32x4*)(xa0 + kb + 4));
    u32x4 a1l = __builtin_nontemporal_load((const u32x4*)(xa1 + kb));
    u32x4 a1h = __builtin_nontemporal_load((const u32x4*)(xa1 + kb + 4));
    bf16x8 a0 = pack8t(a0l, a0h);
    bf16x8 a1 = pack8t(a1l, a1h);
#pragma unroll
    for (int t = 0; t < 8; t++) {
      const unsigned short* bp = w1t + (size_t)(cw + t * 16 + m) * FIN + kb + kg * 8;
      bf16x8 b = __builtin_bit_cast(bf16x8, *(const ushort8*)bp);
      acc[0][t] = __builtin_amdgcn_mfma_f32_16x16x32_bf16(a0, b, acc[0][t], 0, 0, 0);
      acc[1][t] = __builtin_amdgcn_mfma_f32_16x16x32_bf16(a1, b, acc[1][t], 0, 0, 0);
    }
  }
#pragma unroll
  for (int rt = 0; rt < 2; rt++)
#pragma unroll
    for (int t = 0; t < 8; t++)
#pragma unroll
      for (int r = 0; r < 4; r++) {
        int row = r0 + rt * 16 + kg * 4 + r;
        int col = cw + t * 16 + m;
        h1[(size_t)row * FH + col] = f2bf(acc[rt][t][r]);   // normal store: want h1 in LLC
      }
}

// ---------------- aggregate L1 + bias + relu + dropout -> hidden (f32) ----------------
// one wave per node; lane owns 8 contiguous channels [8*lane, 8*lane+8)

__global__ __launch_bounds__(256) void k_agg1(const unsigned short* __restrict__ h1,
                                              const int* __restrict__ rowptr,
                                              const int* __restrict__ src_sorted,
                                              const float* __restrict__ dinv_src,
                                              const float* __restrict__ dinv,
                                              const float* __restrict__ b1,
                                              float* __restrict__ hidden) {
  int i = blockIdx.x * 4 + (threadIdx.x >> 6);
  int lane = threadIdx.x & 63;
  int rs = rowptr[i], re = rowptr[i + 1];
  float di = dinv[i];
  int c = lane << 3;                         // 8 channels per lane

  // dropout mask bits for my 8 channels (bit j set = DROP)
  unsigned flat = (unsigned)i * FH + (unsigned)c;
  unsigned mb = 0;
#pragma unroll
  for (int j = 0; j < 8; j++) mb |= (tf_bits(0u, flat + j) >> 31) << j;

  float acc[8] = {0, 0, 0, 0, 0, 0, 0, 0};

  for (int base = rs; base < re; base += 64) {
    int n = re - base; if (n > 64) n = 64;
    int myi = 0; float myw = 0.0f;
    if (lane < n) {
      myi = __builtin_nontemporal_load(&src_sorted[base + lane]);
      myw = __builtin_nontemporal_load(&dinv_src[base + lane]);
    }
    for (int j = 0; j < n; j++) {
      int s = __shfl(myi, j);
      float wgt = __shfl(myw, j);
      uint4 hv = *(const uint4*)(h1 + (size_t)s * FH + c);  // cached: h1 LLC-resident
      acc[0] += wgt * blo(hv.x); acc[1] += wgt * bhi(hv.x);
      acc[2] += wgt * blo(hv.y); acc[3] += wgt * bhi(hv.y);
      acc[4] += wgt * blo(hv.z); acc[5] += wgt * bhi(hv.z);
      acc[6] += wgt * blo(hv.w); acc[7] += wgt * bhi(hv.w);
    }
  }
  { // self loop, weight di
    uint4 hv = *(const uint4*)(h1 + (size_t)i * FH + c);
    acc[0] += di * blo(hv.x); acc[1] += di * bhi(hv.x);
    acc[2] += di * blo(hv.y); acc[3] += di * bhi(hv.y);
    acc[4] += di * blo(hv.z); acc[5] += di * bhi(hv.z);
    acc[6] += di * blo(hv.w); acc[7] += di * bhi(hv.w);
  }

  float4 bA = *(const float4*)(b1 + c);
  float4 bB = *(const float4*)(b1 + c + 4);
  float bv[8] = {bA.x, bA.y, bA.z, bA.w, bB.x, bB.y, bB.z, bB.w};
  f32x4 o0, o1;
#pragma unroll
  for (int j = 0; j < 8; j++) {
    float v = fmaxf(acc[j] * di + bv[j], 0.0f);
    v = ((mb >> j) & 1u) ? 0.0f : v * 2.0f;
    if (j < 4) o0[j] = v; else o1[j - 4] = v;
  }
  float* hp = hidden + (size_t)i * FH + c;
  // hidden is a 205 MB write stream re-read only by gemm2: bypass LLC to keep h1 hot
  __builtin_nontemporal_store(o0, (f32x4*)hp);
  __builtin_nontemporal_store(o1, (f32x4*)(hp + 4));
}

// ---------------- GEMM2: h2[N,40] = hidden[N,512] @ W2 (bf16 MFMA, cols padded 48) ----------------

__global__ __launch_bounds__(256) void k_gemm2(const float* __restrict__ hidden,
                                               const unsigned short* __restrict__ w2t,
                                               float* __restrict__ h2) {
  int wid = blockIdx.x * 4 + (threadIdx.x >> 6);
  if (wid >= N_NODES / 16) return;
  int lane = threadIdx.x & 63;
  int m = lane & 15, kg = lane >> 4;
  int r0 = wid * 16;
  f32x4 acc[3];
#pragma unroll
  for (int t = 0; t < 3; t++)
#pragma unroll
    for (int r = 0; r < 4; r++) acc[t][r] = 0.0f;

  const float* ap = hidden + (size_t)(r0 + m) * FH + kg * 8;
#pragma unroll 8
  for (int kc = 0; kc < 16; kc++) {
    int kb = kc * 32;
    // hidden read exactly once: non-temporal, keep LLC for h2/w2t
    u32x4 al = __builtin_nontemporal_load((const u32x4*)(ap + kb));
    u32x4 ah = __builtin_nontemporal_load((const u32x4*)(ap + kb + 4));
    bf16x8 a = pack8t(al, ah);
#pragma unroll
    for (int t = 0; t < 3; t++) {
      bf16x8 b = __builtin_bit_cast(bf16x8,
          *(const ushort8*)(w2t + (size_t)(t * 16 + m) * FH + kb + kg * 8));
      acc[t] = __builtin_amdgcn_mfma_f32_16x16x32_bf16(a, b, acc[t], 0, 0, 0);
    }
  }
#pragma unroll
  for (int t = 0; t < 3; t++)
#pragma unroll
    for (int r = 0; r < 4; r++) {
      int row = r0 + kg * 4 + r;
      int col = t * 16 + m;
      if (col < FO) h2[(size_t)row * FO + col] = acc[t][r];   // normal: h2 LLC-resident
    }
}

// ---------------- aggregate L2 + bias -> out (f32) ----------------

__global__ __launch_bounds__(256) void k_agg2(const float* __restrict__ h2,
                                              const int* __restrict__ rowptr,
                                              const int* __restrict__ src_sorted,
                                              const float* __restrict__ dinv_src,
                                              const float* __restrict__ dinv,
                                              const float* __restrict__ b2,
                                              float* __restrict__ out) {
  int i = blockIdx.x * 4 + (threadIdx.x >> 6);
  int lane = threadIdx.x & 63;
  int rs = rowptr[i], re = rowptr[i + 1];
  float di = dinv[i];
  float acc = 0.0f;

  for (int base = rs; base < re; base += 64) {
    int n = re - base; if (n > 64) n = 64;
    int myi = 0; float myw = 0.0f;
    if (lane < n) {
      myi = __builtin_nontemporal_load(&src_sorted[base + lane]);
      myw = __builtin_nontemporal_load(&dinv_src[base + lane]);
    }
    for (int j = 0; j < n; j++) {
      int s = __shfl(myi, j);
      float wgt = __shfl(myw, j);
      if (lane < FO) acc += wgt * h2[(size_t)s * FO + lane];  // cached: h2 LLC-resident
    }
  }
  if (lane < FO) {
    acc += di * h2[(size_t)i * FO + lane];
    float v = acc * di + b2[lane];
    __builtin_nontemporal_store(v, &out[(size_t)i * FO + lane]);
  }
}

// ---------------- launcher ----------------

extern "C" void kernel_launch(void* const* d_in, const int* in_sizes, int n_in,
                              void* d_out, int out_size, void* d_ws, size_t ws_size,
                              hipStream_t stream) {
  const float* x  = (const float*)d_in[0];
  const int* ei   = (const int*)d_in[1];
  const float* w1 = (const float*)d_in[2];
  const float* b1 = (const float*)d_in[3];
  const float* w2 = (const float*)d_in[4];
  const float* b2 = (const float*)d_in[5];

  char* ws = (char*)d_ws;
  float* dinv            = (float*)(ws + O_DINV);
  int* cnt               = (int*)(ws + O_CNT);
  int* rowptr            = (int*)(ws + O_ROWPTR);
  int* cur               = (int*)(ws + O_CUR);
  int* src_sorted        = (int*)(ws + O_SRC);
  float* dinv_src        = (float*)(ws + O_DSRC);
  unsigned short* w1t    = (unsigned short*)(ws + O_W1T);
  unsigned short* w2t    = (unsigned short*)(ws + O_W2T);
  unsigned short* h1     = (unsigned short*)(ws + O_H1);
  float* h2              = (float*)(ws + O_H2);
  int* partials          = (int*)(ws + O_PART);
  int* chunk_base        = (int*)(ws + O_CBASE);

  float* outp   = (float*)d_out;                       // [N,40]
  float* hidden = outp + (size_t)N_NODES * FO;         // [N,512]

  const int* srcA = ei;             // edge_index[0]
  const int* dstA = ei + N_EDGES;   // edge_index[1]

  hipMemsetAsync(cnt, 0, N_NODES * sizeof(int), stream);
  k_count<<<(N_EDGES + 255) / 256, 256, 0, stream>>>(dstA, cnt);
  k_scan1<<<NCHUNK, 256, 0, stream>>>(cnt, rowptr, partials, dinv);
  k_scan2<<<1, 512, 0, stream>>>(partials, chunk_base);
  k_scan3<<<(N_NODES + 1 + 255) / 256, 256, 0, stream>>>(rowptr, chunk_base, cur);
  k_scatter<<<(N_EDGES + 255) / 256, 256, 0, stream>>>(srcA, dstA, dinv, cur,
                                                       src_sorted, dinv_src);
  k_tw<<<(FIN * FH + 48 * FH) / 256, 256, 0, stream>>>(w1, w2, w1t, w2t);
  k_gemm1<<<N_NODES / 32, 256, 0, stream>>>(x, w1t, h1);
  k_agg1<<<N_NODES / 4, 256, 0, stream>>>(h1, rowptr, src_sorted, dinv_src, dinv,
                                          b1, hidden);
  k_gemm2<<<(N_NODES / 16 + 3) / 4, 256, 0, stream>>>(hidden, w2t, h2);
  k_agg2<<<N_NODES / 4, 256, 0, stream>>>(h2, rowptr, src_sorted, dinv_src, dinv,
                                          b2, outp);
}